// Round 8
// baseline (73.016 us; speedup 1.0000x reference)
//
#include <hip/hip_runtime.h>
#include <hip/hip_bf16.h>

// score[e] = W2 . relu( W1a.emb[src] + W1b.emb[dst] + b1 ) + b2
// P[n][jj] = dot(emb[n,:], W1col jj) (+ b1[jj] for jj<128), stored bf16.
// precompute: [M x 128] x [128 x 256] MFMA GEMM. A-fragments loaded DIRECTLY from
//   global emb (16 full 128B lines/inst, L1-shared across waves) + in-reg cvt_pk;
//   no staging phase, ONE barrier (f32 C-tile LDS bounce -> coalesced bf16 streamout).
// edge: A[16 edges][K=128]=relu(Ps+Pd) x B[K][16]=W2 (all cols equal), 32 edges/wave.
//   Edge phase is at the random-gather service roofline (~3.1 TB/s, ~130MB; invariant
//   across 3 structures; concurrency >> Little's-law requirement).

#define H   128
#define NJJ 256
#define BM  32
#define EPW 32
#define CPAD_F32 260   // f32 C-tile row stride (mult of 4 -> 16B-aligned rows)

typedef __attribute__((ext_vector_type(8))) short  frag_ab;   // 8 bf16
typedef __attribute__((ext_vector_type(4))) float  f32x4;
typedef __attribute__((ext_vector_type(4))) unsigned int   uint4v;

__device__ __forceinline__ unsigned short f2bf(float x) {   // RNE fp32->bf16
    unsigned int u = __float_as_uint(x);
    unsigned int r = u + 0x7FFFu + ((u >> 16) & 1u);
    return (unsigned short)(r >> 16);
}

__device__ __forceinline__ unsigned int pk_bf16(float lo, float hi) {  // RNE pair pack
    unsigned int r;
    asm("v_cvt_pk_bf16_f32 %0, %1, %2" : "=v"(r) : "v"(lo), "v"(hi));
    return r;
}

__device__ __forceinline__ frag_ab relu_sum(uint4v s, uint4v d) {
    uint4v r;
#pragma unroll
    for (int p = 0; p < 4; ++p) {
        float sl = __uint_as_float(s[p] << 16);
        float sh = __uint_as_float(s[p] & 0xFFFF0000u);
        float dl = __uint_as_float(d[p] << 16);
        float dh = __uint_as_float(d[p] & 0xFFFF0000u);
        float l = sl + dl; l = l > 0.f ? l : 0.f;
        float h = sh + dh; h = h > 0.f ? h : 0.f;
        r[p] = pk_bf16(l, h);
    }
    return __builtin_bit_cast(frag_ab, r);
}

// W1 -> bf16 fragment-ready layout W1f; W2 -> bf16 W2c.
// W1f chunk layout: chunk = ((wid*4+cf)*4+ks)*64 + lane ; elem e in [0,8)
//   col = wid*64 + (lane&15) + cf*16 ; k = ks*32 + (lane>>4)*8 + e
__global__ __launch_bounds__(256)
void convert_weights(const float* __restrict__ W1, const float* __restrict__ W2,
                     unsigned short* __restrict__ W1f, unsigned short* __restrict__ W2c) {
    if (blockIdx.x == 128) {
        if (threadIdx.x < H) W2c[threadIdx.x] = f2bf(W2[threadIdx.x]);
        return;
    }
    int idx = blockIdx.x * 256 + threadIdx.x;          // [0, 32768)
    int e     = idx & 7;
    int chunk = idx >> 3;
    int lane  = chunk & 63;
    int ks    = (chunk >> 6) & 3;
    int cf    = (chunk >> 8) & 3;
    int wid   = chunk >> 10;
    int col   = wid * 64 + (lane & 15) + cf * 16;
    int k     = ks * 32 + (lane >> 4) * 8 + e;
    W1f[idx] = f2bf(W1[(size_t)(col & 127) * 256 + (size_t)(col >> 7) * H + k]);
}

__global__ __launch_bounds__(256)
void precompute_P_mfma(const float* __restrict__ emb,
                       const unsigned short* __restrict__ W1f,
                       const float* __restrict__ b1,
                       unsigned short* __restrict__ P,
                       int n_nodes) {
    __shared__ __align__(16) float ldsC[BM * CPAD_F32];   // 33280 B
    int tid  = threadIdx.x;
    int lane = tid & 63;
    int wid  = tid >> 6;
    int block0 = blockIdx.x * BM;
    if (block0 + BM > n_nodes) block0 = n_nodes - BM;   // overlap tail (same values rewritten)
    if (block0 < 0) block0 = 0;

    // B fragments: fully coalesced 1KB/inst from fragment-ready W1f (L2-hot)
    const frag_ab* wf = (const frag_ab*)W1f;
    frag_ab Bf[4][4];
#pragma unroll
    for (int cf = 0; cf < 4; ++cf)
#pragma unroll
        for (int ks = 0; ks < 4; ++ks)
            Bf[cf][ks] = wf[(((size_t)wid * 4 + cf) * 4 + ks) * 64 + lane];

    // A fragments DIRECT from global (no LDS staging, no barrier):
    // per inst: 16 rows x full 128B lines; 4 waves share the tile via L1.
    f32x4 acc[2][4];
#pragma unroll
    for (int mf = 0; mf < 2; ++mf)
#pragma unroll
        for (int cf = 0; cf < 4; ++cf) acc[mf][cf] = (f32x4){0.f, 0.f, 0.f, 0.f};

    int row16 = lane & 15;
    int g     = lane >> 4;
    const float* a0 = emb + (size_t)(block0 + row16) * H + g * 8;

#pragma unroll
    for (int ks = 0; ks < 4; ++ks) {
        frag_ab Af[2];
#pragma unroll
        for (int mf = 0; mf < 2; ++mf) {
            const float4* p = (const float4*)(a0 + mf * 16 * H + ks * 32);
            float4 a = p[0], b = p[1];
            uint4v w;
            w[0] = pk_bf16(a.x, a.y);
            w[1] = pk_bf16(a.z, a.w);
            w[2] = pk_bf16(b.x, b.y);
            w[3] = pk_bf16(b.z, b.w);
            Af[mf] = __builtin_bit_cast(frag_ab, w);
        }
#pragma unroll
        for (int mf = 0; mf < 2; ++mf)
#pragma unroll
            for (int cf = 0; cf < 4; ++cf)
                acc[mf][cf] = __builtin_amdgcn_mfma_f32_16x16x32_bf16(
                    Af[mf], Bf[cf][ks], acc[mf][cf], 0, 0, 0);
    }

    // epilogue pt1: +b1, write f32 C-tile to padded LDS (only barrier in kernel)
    {
        int colbase = wid * 64 + row16;
        int rbase   = g * 4;
        float b1c[4];
#pragma unroll
        for (int cf = 0; cf < 4; ++cf) {
            int col = colbase + cf * 16;
            b1c[cf] = (col < H) ? b1[col] : 0.f;
        }
#pragma unroll
        for (int mf = 0; mf < 2; ++mf)
#pragma unroll
            for (int cf = 0; cf < 4; ++cf) {
                int col = colbase + cf * 16;
#pragma unroll
                for (int r = 0; r < 4; ++r) {
                    int row = mf * 16 + rbase + r;
                    ldsC[row * CPAD_F32 + col] = acc[mf][cf][r] + b1c[cf];
                }
            }
    }
    __syncthreads();

    // epilogue pt2: stream out; 32B f32 LDS -> 4x cvt_pk -> 16B bf16 store (full lines)
#pragma unroll
    for (int it = 0; it < 4; ++it) {
        int c   = it * 256 + tid;        // 8-col chunk id, [0, 1024)
        int row = c >> 5;
        int off = c & 31;
        const float4* s = (const float4*)(ldsC + row * CPAD_F32 + off * 8);
        float4 x = s[0], y = s[1];
        uint4v o;
        o[0] = pk_bf16(x.x, x.y);
        o[1] = pk_bf16(x.z, x.w);
        o[2] = pk_bf16(y.x, y.y);
        o[3] = pk_bf16(y.z, y.w);
        *(uint4v*)((char*)P + (size_t)(block0 + row) * 512 + off * 16) = o;
    }
}

__global__ __launch_bounds__(256)
void edge_score_mfma(const unsigned short* __restrict__ P,
                     const unsigned short* __restrict__ W2c,
                     const float* __restrict__ b2,
                     const int* __restrict__ src,
                     const int* __restrict__ dst,
                     float* __restrict__ out,
                     int n_edges) {
    int lane = threadIdx.x & 63;
    int wave = blockIdx.x * 4 + (threadIdx.x >> 6);
    int e0 = wave * EPW;
    if (e0 >= n_edges) return;

    frag_ab Bf[4];
    {
        int krun = (lane >> 4) * 8;
#pragma unroll
        for (int ks = 0; ks < 4; ++ks)
            Bf[ks] = *(const frag_ab*)(W2c + ks * 32 + krun);
    }
    float b2v = b2[0];
    int el = lane & 15;
    int kb = (lane >> 4) * 16;

    int eA = e0 + el;       if (eA > n_edges - 1) eA = n_edges - 1;
    int eB = e0 + 16 + el;  if (eB > n_edges - 1) eB = n_edges - 1;
    const char* pb = (const char*)P;
    const char* sA = pb + (size_t)src[eA] * 512 + kb;
    const char* dA = pb + (size_t)dst[eA] * 512 + 256 + kb;
    const char* sB = pb + (size_t)src[eB] * 512 + kb;
    const char* dB = pb + (size_t)dst[eB] * 512 + 256 + kb;

    uint4v rsA[4], rdA[4], rsB[4], rdB[4];
#pragma unroll
    for (int ks = 0; ks < 4; ++ks) {        // 16 independent gathers in flight
        rsA[ks] = *(const uint4v*)(sA + ks * 64);
        rdA[ks] = *(const uint4v*)(dA + ks * 64);
        rsB[ks] = *(const uint4v*)(sB + ks * 64);
        rdB[ks] = *(const uint4v*)(dB + ks * 64);
    }

    f32x4 accA = (f32x4){0.f, 0.f, 0.f, 0.f};
    f32x4 accB = (f32x4){0.f, 0.f, 0.f, 0.f};
#pragma unroll
    for (int ks = 0; ks < 4; ++ks) {
        accA = __builtin_amdgcn_mfma_f32_16x16x32_bf16(relu_sum(rsA[ks], rdA[ks]), Bf[ks], accA, 0, 0, 0);
        accB = __builtin_amdgcn_mfma_f32_16x16x32_bf16(relu_sum(rsB[ks], rdB[ks]), Bf[ks], accB, 0, 0, 0);
    }

    if (el == 0) {
        int r0 = (lane >> 4) * 4;
        int ea = e0 + r0, eb = e0 + 16 + r0;
        float4 oA = { accA[0] + b2v, accA[1] + b2v, accA[2] + b2v, accA[3] + b2v };
        float4 oB = { accB[0] + b2v, accB[1] + b2v, accB[2] + b2v, accB[3] + b2v };
        if (eb + 3 < n_edges) {
            *(float4*)(out + ea) = oA;
            *(float4*)(out + eb) = oB;
        } else {
#pragma unroll
            for (int r = 0; r < 4; ++r) {
                if (ea + r < n_edges) out[ea + r] = accA[r] + b2v;
                if (eb + r < n_edges) out[eb + r] = accB[r] + b2v;
            }
        }
    }
}

// Fallback if workspace too small (correctness-first, slow).
__global__ __launch_bounds__(128)
void naive_edge(const float* __restrict__ emb,
                const float* __restrict__ W1,
                const float* __restrict__ b1,
                const float* __restrict__ W2,
                const float* __restrict__ b2,
                const int* __restrict__ src,
                const int* __restrict__ dst,
                float* __restrict__ out,
                int n_edges) {
    __shared__ float es[H], ed[H];
    __shared__ float red[2];
    int e = blockIdx.x;
    if (e >= n_edges) return;
    int j = threadIdx.x;
    int s = src[e], d = dst[e];
    es[j] = emb[(size_t)s * H + j];
    ed[j] = emb[(size_t)d * H + j];
    __syncthreads();
    const float* w = W1 + (size_t)j * 256;
    float acc = b1[j];
    for (int k = 0; k < H; ++k) acc += es[k] * w[k] + ed[k] * w[H + k];
    acc = acc > 0.f ? acc : 0.f;
    float p = acc * W2[j];
#pragma unroll
    for (int off = 32; off; off >>= 1) p += __shfl_xor(p, off, 64);
    int lane = j & 63, wid = j >> 6;
    if (lane == 0) red[wid] = p;
    __syncthreads();
    if (j == 0) out[e] = red[0] + red[1] + b2[0];
}

extern "C" void kernel_launch(void* const* d_in, const int* in_sizes, int n_in,
                              void* d_out, int out_size, void* d_ws, size_t ws_size,
                              hipStream_t stream) {
    const float* emb = (const float*)d_in[0];   // [N, 128]
    const float* W1  = (const float*)d_in[1];   // [128, 256]
    const float* b1  = (const float*)d_in[2];   // [128]
    const float* W2  = (const float*)d_in[3];   // [1, 128]
    const float* b2  = (const float*)d_in[4];   // [1]
    const int*   src = (const int*)d_in[5];     // [E]
    const int*   dst = (const int*)d_in[6];     // [E]
    float* out = (float*)d_out;

    int n_nodes = in_sizes[0] / H;
    int n_edges = in_sizes[5];

    size_t needP = (size_t)n_nodes * NJJ * sizeof(unsigned short);
    size_t offW1 = (needP + 255) & ~(size_t)255;
    size_t offW2 = offW1 + (size_t)NJJ * H * sizeof(unsigned short);
    size_t need  = offW2 + 256;

    if (ws_size >= need && n_nodes >= BM) {
        unsigned short* P   = (unsigned short*)d_ws;
        unsigned short* W1f = (unsigned short*)((char*)d_ws + offW1);
        unsigned short* W2c = (unsigned short*)((char*)d_ws + offW2);
        convert_weights<<<129, 256, 0, stream>>>(W1, W2, W1f, W2c);
        int grid1 = (n_nodes + BM - 1) / BM;
        precompute_P_mfma<<<grid1, 256, 0, stream>>>(emb, W1f, b1, P, n_nodes);
        int grid2 = (n_edges + EPW * 4 - 1) / (EPW * 4);
        edge_score_mfma<<<grid2, 256, 0, stream>>>(P, W2c, b2, src, dst, out, n_edges);
    } else {
        naive_edge<<<n_edges, 128, 0, stream>>>(emb, W1, b1, W2, b2, src, dst, out, n_edges);
    }
}

// Round 9
// 64.409 us; speedup vs baseline: 1.1336x; 1.1336x over previous
//
#include <hip/hip_runtime.h>
#include <hip/hip_bf16.h>

// score[e] = W2 . relu( W1a.emb[src] + W1b.emb[dst] + b1 ) + b2
// P[n][jj] = dot(emb[n,:], W1col jj) (+ b1[jj] for jj<128), stored bf16.
// precompute: [M x 128] x [128 x 256] MFMA GEMM.
//   A staged fp32 via global_load_lds (async DMA, width=16, zero staging VALU),
//   XOR-swizzle applied on the GLOBAL source (linear LDS dest) and on the ds_read
//   (both-sides involution, rule 21); fp32->bf16 via cvt_pk at fragment build.
//   f32 C-tile LDS bounce -> packed cvt_pk -> coalesced full-line bf16 P stores.
// edge: A[16 edges][K=128]=relu(Ps+Pd) x B[K][16]=W2 (all cols equal), 32 edges/wave.
//   Edge phase is at the random-gather service roofline (~3.1 TB/s, ~130MB compulsory;
//   invariant across 3 structures).

#define H   128
#define NJJ 256
#define BM  32
#define EPW 32
#define CPAD_F32 260   // f32 C-tile row stride (mult of 4 -> 16B-aligned rows)

typedef __attribute__((ext_vector_type(8))) short  frag_ab;   // 8 bf16
typedef __attribute__((ext_vector_type(4))) float  f32x4;
typedef __attribute__((ext_vector_type(4))) unsigned int   uint4v;

__device__ __forceinline__ unsigned short f2bf(float x) {   // RNE fp32->bf16
    unsigned int u = __float_as_uint(x);
    unsigned int r = u + 0x7FFFu + ((u >> 16) & 1u);
    return (unsigned short)(r >> 16);
}

__device__ __forceinline__ unsigned int pk_bf16(float lo, float hi) {  // RNE pair pack
    unsigned int r;
    asm("v_cvt_pk_bf16_f32 %0, %1, %2" : "=v"(r) : "v"(lo), "v"(hi));
    return r;
}

__device__ __forceinline__ frag_ab relu_sum(uint4v s, uint4v d) {
    uint4v r;
#pragma unroll
    for (int p = 0; p < 4; ++p) {
        float sl = __uint_as_float(s[p] << 16);
        float sh = __uint_as_float(s[p] & 0xFFFF0000u);
        float dl = __uint_as_float(d[p] << 16);
        float dh = __uint_as_float(d[p] & 0xFFFF0000u);
        float l = sl + dl; l = l > 0.f ? l : 0.f;
        float h = sh + dh; h = h > 0.f ? h : 0.f;
        r[p] = pk_bf16(l, h);
    }
    return __builtin_bit_cast(frag_ab, r);
}

// W1 -> bf16 fragment-ready layout W1f; W2 -> bf16 W2c.
// W1f chunk layout: chunk = ((wid*4+cf)*4+ks)*64 + lane ; elem e in [0,8)
//   col = wid*64 + (lane&15) + cf*16 ; k = ks*32 + (lane>>4)*8 + e
__global__ __launch_bounds__(256)
void convert_weights(const float* __restrict__ W1, const float* __restrict__ W2,
                     unsigned short* __restrict__ W1f, unsigned short* __restrict__ W2c) {
    if (blockIdx.x == 128) {
        if (threadIdx.x < H) W2c[threadIdx.x] = f2bf(W2[threadIdx.x]);
        return;
    }
    int idx = blockIdx.x * 256 + threadIdx.x;          // [0, 32768)
    int e     = idx & 7;
    int chunk = idx >> 3;
    int lane  = chunk & 63;
    int ks    = (chunk >> 6) & 3;
    int cf    = (chunk >> 8) & 3;
    int wid   = chunk >> 10;
    int col   = wid * 64 + (lane & 15) + cf * 16;
    int k     = ks * 32 + (lane >> 4) * 8 + e;
    W1f[idx] = f2bf(W1[(size_t)(col & 127) * 256 + (size_t)(col >> 7) * H + k]);
}

// swizzled 16B-chunk position within a 512B fp32 row: involution c <-> c'
__device__ __forceinline__ int swz_chunk(int c, int row) {
    return (c & ~7) | ((c ^ row) & 7);
}

__global__ __launch_bounds__(256)
void precompute_P_mfma(const float* __restrict__ emb,
                       const unsigned short* __restrict__ W1f,
                       const float* __restrict__ b1,
                       unsigned short* __restrict__ P,
                       int n_nodes) {
    __shared__ __align__(1024) float ldsbuf[BM * CPAD_F32];   // 33280B
    float* ldsA = ldsbuf;   // fp32 A-tile 32x128 (16KB, swizzled), aliased with C
    float* ldsC = ldsbuf;   // f32 C-tile 32 x 260 (after post-MFMA barrier)

    int tid  = threadIdx.x;
    int lane = tid & 63;
    int wid  = tid >> 6;
    int block0 = blockIdx.x * BM;
    if (block0 + BM > n_nodes) block0 = n_nodes - BM;   // overlap tail (same values rewritten)
    if (block0 < 0) block0 = 0;

    // B fragments: fully coalesced 1KB/inst from fragment-ready W1f (L2-hot); issue first
    const frag_ab* wf = (const frag_ab*)W1f;
    frag_ab Bf[4][4];
#pragma unroll
    for (int cf = 0; cf < 4; ++cf)
#pragma unroll
        for (int ks = 0; ks < 4; ++ks)
            Bf[cf][ks] = wf[(((size_t)wid * 4 + cf) * 4 + ks) * 64 + lane];

    // stage A tile fp32 via async DMA: 4 x global_load_lds(16B). Linear LDS dest
    // (HW: wave-uniform base + lane*16); swizzle applied on the global source.
    {
#pragma unroll
        for (int j = 0; j < 4; ++j) {
            int row = wid * 8 + j * 2 + (lane >> 5);     // LDS row this lane fills
            int cp  = lane & 31;                         // linear chunk pos in row
            int c   = swz_chunk(cp, row);                // source chunk (involution)
            const float* g = emb + (size_t)(block0 + row) * H + c * 4;
            void* l = (char*)ldsA + wid * 4096 + j * 1024;
            __builtin_amdgcn_global_load_lds(
                (const __attribute__((address_space(1))) void*)g,
                (__attribute__((address_space(3))) void*)l, 16, 0, 0);
        }
    }
    __syncthreads();   // drains vmcnt -> A-tile ready

    // MFMA: each wave computes [32 rows x 64 cols]; A-frags: swizzled fp32 ds_read + cvt_pk
    f32x4 acc[2][4];
#pragma unroll
    for (int mf = 0; mf < 2; ++mf)
#pragma unroll
        for (int cf = 0; cf < 4; ++cf) acc[mf][cf] = (f32x4){0.f, 0.f, 0.f, 0.f};

    int row16 = lane & 15;
    int g4    = lane >> 4;
#pragma unroll
    for (int ks = 0; ks < 4; ++ks) {
        frag_ab Af[2];
#pragma unroll
        for (int mf = 0; mf < 2; ++mf) {
            int row   = mf * 16 + row16;
            int cbase = ks * 8 + g4 * 2;     // 16B-chunk index of k-run start
            const char* base = (const char*)ldsA + row * 512;
            float4 x = *(const float4*)(base + (swz_chunk(cbase,     row) << 4));
            float4 y = *(const float4*)(base + (swz_chunk(cbase + 1, row) << 4));
            uint4v w;
            w[0] = pk_bf16(x.x, x.y);
            w[1] = pk_bf16(x.z, x.w);
            w[2] = pk_bf16(y.x, y.y);
            w[3] = pk_bf16(y.z, y.w);
            Af[mf] = __builtin_bit_cast(frag_ab, w);
        }
#pragma unroll
        for (int mf = 0; mf < 2; ++mf)
#pragma unroll
            for (int cf = 0; cf < 4; ++cf)
                acc[mf][cf] = __builtin_amdgcn_mfma_f32_16x16x32_bf16(
                    Af[mf], Bf[cf][ks], acc[mf][cf], 0, 0, 0);
    }

    __syncthreads();   // all A reads done -> safe to overwrite ldsbuf with f32 C-tile

    // epilogue pt1: +b1, write f32 C-tile to padded LDS
    {
        int colbase = wid * 64 + row16;
        int rbase   = g4 * 4;
        float b1c[4];
#pragma unroll
        for (int cf = 0; cf < 4; ++cf) {
            int col = colbase + cf * 16;
            b1c[cf] = (col < H) ? b1[col] : 0.f;
        }
#pragma unroll
        for (int mf = 0; mf < 2; ++mf)
#pragma unroll
            for (int cf = 0; cf < 4; ++cf) {
                int col = colbase + cf * 16;
#pragma unroll
                for (int r = 0; r < 4; ++r) {
                    int row = mf * 16 + rbase + r;
                    ldsC[row * CPAD_F32 + col] = acc[mf][cf][r] + b1c[cf];
                }
            }
    }
    __syncthreads();

    // epilogue pt2: stream out; 32B f32 LDS -> 4x cvt_pk -> 16B bf16 store (full lines)
#pragma unroll
    for (int it = 0; it < 4; ++it) {
        int c   = it * 256 + tid;        // 8-col chunk id, [0, 1024)
        int row = c >> 5;
        int off = c & 31;
        const float4* s = (const float4*)(ldsC + row * CPAD_F32 + off * 8);
        float4 x = s[0], y = s[1];
        uint4v o;
        o[0] = pk_bf16(x.x, x.y);
        o[1] = pk_bf16(x.z, x.w);
        o[2] = pk_bf16(y.x, y.y);
        o[3] = pk_bf16(y.z, y.w);
        *(uint4v*)((char*)P + (size_t)(block0 + row) * 512 + off * 16) = o;
    }
}

__global__ __launch_bounds__(256)
void edge_score_mfma(const unsigned short* __restrict__ P,
                     const unsigned short* __restrict__ W2c,
                     const float* __restrict__ b2,
                     const int* __restrict__ src,
                     const int* __restrict__ dst,
                     float* __restrict__ out,
                     int n_edges) {
    int lane = threadIdx.x & 63;
    int wave = blockIdx.x * 4 + (threadIdx.x >> 6);
    int e0 = wave * EPW;
    if (e0 >= n_edges) return;

    frag_ab Bf[4];
    {
        int krun = (lane >> 4) * 8;
#pragma unroll
        for (int ks = 0; ks < 4; ++ks)
            Bf[ks] = *(const frag_ab*)(W2c + ks * 32 + krun);
    }
    float b2v = b2[0];
    int el = lane & 15;
    int kb = (lane >> 4) * 16;

    int eA = e0 + el;       if (eA > n_edges - 1) eA = n_edges - 1;
    int eB = e0 + 16 + el;  if (eB > n_edges - 1) eB = n_edges - 1;
    const char* pb = (const char*)P;
    const char* sA = pb + (size_t)src[eA] * 512 + kb;
    const char* dA = pb + (size_t)dst[eA] * 512 + 256 + kb;
    const char* sB = pb + (size_t)src[eB] * 512 + kb;
    const char* dB = pb + (size_t)dst[eB] * 512 + 256 + kb;

    uint4v rsA[4], rdA[4], rsB[4], rdB[4];
#pragma unroll
    for (int ks = 0; ks < 4; ++ks) {        // 16 independent gathers in flight
        rsA[ks] = *(const uint4v*)(sA + ks * 64);
        rdA[ks] = *(const uint4v*)(dA + ks * 64);
        rsB[ks] = *(const uint4v*)(sB + ks * 64);
        rdB[ks] = *(const uint4v*)(dB + ks * 64);
    }

    f32x4 accA = (f32x4){0.f, 0.f, 0.f, 0.f};
    f32x4 accB = (f32x4){0.f, 0.f, 0.f, 0.f};
#pragma unroll
    for (int ks = 0; ks < 4; ++ks) {
        accA = __builtin_amdgcn_mfma_f32_16x16x32_bf16(relu_sum(rsA[ks], rdA[ks]), Bf[ks], accA, 0, 0, 0);
        accB = __builtin_amdgcn_mfma_f32_16x16x32_bf16(relu_sum(rsB[ks], rdB[ks]), Bf[ks], accB, 0, 0, 0);
    }

    if (el == 0) {
        int r0 = (lane >> 4) * 4;
        int ea = e0 + r0, eb = e0 + 16 + r0;
        float4 oA = { accA[0] + b2v, accA[1] + b2v, accA[2] + b2v, accA[3] + b2v };
        float4 oB = { accB[0] + b2v, accB[1] + b2v, accB[2] + b2v, accB[3] + b2v };
        if (eb + 3 < n_edges) {
            *(float4*)(out + ea) = oA;
            *(float4*)(out + eb) = oB;
        } else {
#pragma unroll
            for (int r = 0; r < 4; ++r) {
                if (ea + r < n_edges) out[ea + r] = accA[r] + b2v;
                if (eb + r < n_edges) out[eb + r] = accB[r] + b2v;
            }
        }
    }
}

// Fallback if workspace too small (correctness-first, slow).
__global__ __launch_bounds__(128)
void naive_edge(const float* __restrict__ emb,
                const float* __restrict__ W1,
                const float* __restrict__ b1,
                const float* __restrict__ W2,
                const float* __restrict__ b2,
                const int* __restrict__ src,
                const int* __restrict__ dst,
                float* __restrict__ out,
                int n_edges) {
    __shared__ float es[H], ed[H];
    __shared__ float red[2];
    int e = blockIdx.x;
    if (e >= n_edges) return;
    int j = threadIdx.x;
    int s = src[e], d = dst[e];
    es[j] = emb[(size_t)s * H + j];
    ed[j] = emb[(size_t)d * H + j];
    __syncthreads();
    const float* w = W1 + (size_t)j * 256;
    float acc = b1[j];
    for (int k = 0; k < H; ++k) acc += es[k] * w[k] + ed[k] * w[H + k];
    acc = acc > 0.f ? acc : 0.f;
    float p = acc * W2[j];
#pragma unroll
    for (int off = 32; off; off >>= 1) p += __shfl_xor(p, off, 64);
    int lane = j & 63, wid = j >> 6;
    if (lane == 0) red[wid] = p;
    __syncthreads();
    if (j == 0) out[e] = red[0] + red[1] + b2[0];
}

extern "C" void kernel_launch(void* const* d_in, const int* in_sizes, int n_in,
                              void* d_out, int out_size, void* d_ws, size_t ws_size,
                              hipStream_t stream) {
    const float* emb = (const float*)d_in[0];   // [N, 128]
    const float* W1  = (const float*)d_in[1];   // [128, 256]
    const float* b1  = (const float*)d_in[2];   // [128]
    const float* W2  = (const float*)d_in[3];   // [1, 128]
    const float* b2  = (const float*)d_in[4];   // [1]
    const int*   src = (const int*)d_in[5];     // [E]
    const int*   dst = (const int*)d_in[6];     // [E]
    float* out = (float*)d_out;

    int n_nodes = in_sizes[0] / H;
    int n_edges = in_sizes[5];

    size_t needP = (size_t)n_nodes * NJJ * sizeof(unsigned short);
    size_t offW1 = (needP + 255) & ~(size_t)255;
    size_t offW2 = offW1 + (size_t)NJJ * H * sizeof(unsigned short);
    size_t need  = offW2 + 256;

    if (ws_size >= need && n_nodes >= BM) {
        unsigned short* P   = (unsigned short*)d_ws;
        unsigned short* W1f = (unsigned short*)((char*)d_ws + offW1);
        unsigned short* W2c = (unsigned short*)((char*)d_ws + offW2);
        convert_weights<<<129, 256, 0, stream>>>(W1, W2, W1f, W2c);
        int grid1 = (n_nodes + BM - 1) / BM;
        precompute_P_mfma<<<grid1, 256, 0, stream>>>(emb, W1f, b1, P, n_nodes);
        int grid2 = (n_edges + EPW * 4 - 1) / (EPW * 4);
        edge_score_mfma<<<grid2, 256, 0, stream>>>(P, W2c, b2, src, dst, out, n_edges);
    } else {
        naive_edge<<<n_edges, 128, 0, stream>>>(emb, W1, b1, W2, b2, src, dst, out, n_edges);
    }
}